// Round 2
// baseline (1177.813 us; speedup 1.0000x reference)
//
#include <hip/hip_runtime.h>
#include <cstdint>
#include <cstddef>

// ---------------------------------------------------------------------------
//   x:    [B=128, T=256, D=1024] fp32
//   Wk:   [1024, 512] per dir    Wr: [128, 512]    bias: [512]
//   xp[dir][t*128+b][512] = x[b,t,:] @ Wk + bias   (bf16, t-major, bias folded)
//   LSTM: 16 seqs/block, gate tiles striped so each wave owns i,f,g,o for the
//   same hidden dims (register-local c update, ONE barrier per step).
// ---------------------------------------------------------------------------

typedef __attribute__((ext_vector_type(8))) short short8;
typedef __attribute__((ext_vector_type(4))) float f32x4;
typedef __attribute__((address_space(1))) unsigned int gas_uint;
typedef __attribute__((address_space(3))) unsigned int las_uint;

__device__ __forceinline__ unsigned short f2b(float f) {
    unsigned int u = __float_as_uint(f);
    u += 0x7FFFu + ((u >> 16) & 1u);          // RNE
    return (unsigned short)(u >> 16);
}
__device__ __forceinline__ float b2f(unsigned short u) {
    return __uint_as_float(((unsigned int)u) << 16);
}
__device__ __forceinline__ float sigmoidf_(float z) { return 1.0f / (1.0f + __expf(-z)); }
__device__ __forceinline__ float tanhf_(float z) {
    float e = __expf(2.0f * z);
    return 1.0f - 2.0f / (e + 1.0f);
}

// async global->LDS 16B: lane writes lds_base(wave-uniform) + lane*16
__device__ __forceinline__ void async_ld16(const unsigned short* g, unsigned short* l) {
    __builtin_amdgcn_global_load_lds(
        (gas_uint*)(uintptr_t)g,
        (las_uint*)(uintptr_t)(unsigned int)(uintptr_t)l,
        16, 0, 0);
}

// ---------------------------------------------------------------------------
// Kernel 1: x fp32 -> bf16
// ---------------------------------------------------------------------------
__global__ void conv_x(const float* __restrict__ x, unsigned short* __restrict__ xb, int n8) {
    int idx = blockIdx.x * blockDim.x + threadIdx.x;
    int stride = gridDim.x * blockDim.x;
    for (int i = idx; i < n8; i += stride) {
        const float4* p = ((const float4*)x) + (size_t)i * 2;
        float4 a = p[0], b = p[1];
        short8 r;
        r[0] = (short)f2b(a.x); r[1] = (short)f2b(a.y);
        r[2] = (short)f2b(a.z); r[3] = (short)f2b(a.w);
        r[4] = (short)f2b(b.x); r[5] = (short)f2b(b.y);
        r[6] = (short)f2b(b.z); r[7] = (short)f2b(b.w);
        *(((short8*)xb) + i) = r;
    }
}

// ---------------------------------------------------------------------------
// Kernel 2: transpose + convert Wk [1024][512] -> Wk_t [512][1024] bf16
// ---------------------------------------------------------------------------
__global__ void conv_wk(const float* __restrict__ wf, const float* __restrict__ wb,
                        unsigned short* __restrict__ wt) {
    int dir = blockIdx.y;
    const float* w = dir ? wb : wf;
    int id = blockIdx.x * blockDim.x + threadIdx.x;
    int g = id >> 10, d = id & 1023;
    wt[(size_t)dir * 524288 + id] = f2b(w[d * 512 + g]);
}

// ---------------------------------------------------------------------------
// Kernel 3: GEMM xp = A[32768,1024] @ Wk_t^T + bias -> bf16 t-major [t*128+b][512]
// 128x128 tile, BK=64, LDK=64, global_load_lds w=16, XOR swizzle chunk^(row&7).
// ---------------------------------------------------------------------------
__global__ __launch_bounds__(256, 2) void gemm_xp(
    const unsigned short* __restrict__ A,
    const unsigned short* __restrict__ Wt,
    const float* __restrict__ bf_, const float* __restrict__ bb_,
    unsigned short* __restrict__ XP)
{
    __shared__ unsigned short As[128 * 64];
    __shared__ unsigned short Bs[128 * 64];

    const int tid  = threadIdx.x;
    const int dir  = blockIdx.z;
    const int tm   = blockIdx.x;             // 0..255
    const int tn   = blockIdx.y;             // 0..3
    const int w    = tid >> 6;
    const int lane = tid & 63;
    const int lanelo = lane & 15;
    const int quad = lane >> 4;
    const int wm = w & 1, wn = w >> 1;

    const unsigned short* Bmat = Wt + (size_t)dir * 524288;
    const float* bias = dir ? bb_ : bf_;
    unsigned short* out = XP + (size_t)dir * 16777216;

    // staging: chunk p = c*256+tid ; row=p>>3 ; logical chunk = (p&7)^(row&7)
    const unsigned short* ga[4];
    const unsigned short* gb[4];
    unsigned short* la[4];
    unsigned short* lb[4];
#pragma unroll
    for (int c = 0; c < 4; ++c) {
        int p = c * 256 + tid;
        int row = p >> 3;
        int lc = (p & 7) ^ (row & 7);
        ga[c] = A    + (size_t)(tm * 128 + row) * 1024 + lc * 8;
        gb[c] = Bmat + (size_t)(tn * 128 + row) * 1024 + lc * 8;
        int ub = (c * 256 + (tid & ~63)) * 8;     // wave-uniform LDS base (elems)
        la[c] = As + ub;
        lb[c] = Bs + ub;
    }

    f32x4 acc[4][4];
#pragma unroll
    for (int i = 0; i < 4; i++)
#pragma unroll
        for (int j = 0; j < 4; j++) acc[i][j] = (f32x4){0.f, 0.f, 0.f, 0.f};

    for (int kt = 0; kt < 16; ++kt) {
        __syncthreads();                          // LDS reads of prev iter done
#pragma unroll
        for (int c = 0; c < 4; ++c) {
            async_ld16(ga[c] + kt * 64, la[c]);
            async_ld16(gb[c] + kt * 64, lb[c]);
        }
        __syncthreads();                          // drains vmcnt -> staged data visible
#pragma unroll
        for (int ks = 0; ks < 2; ++ks) {
            short8 af[4], bfr[4];
#pragma unroll
            for (int i = 0; i < 4; ++i) {
                int row = wm * 64 + i * 16 + lanelo;
                af[i] = *(const short8*)(As + row * 64 + (((ks * 4 + quad) ^ (row & 7)) * 8));
            }
#pragma unroll
            for (int j = 0; j < 4; ++j) {
                int row = wn * 64 + j * 16 + lanelo;
                bfr[j] = *(const short8*)(Bs + row * 64 + (((ks * 4 + quad) ^ (row & 7)) * 8));
            }
#pragma unroll
            for (int i = 0; i < 4; ++i)
#pragma unroll
                for (int j = 0; j < 4; ++j)
                    acc[i][j] = __builtin_amdgcn_mfma_f32_16x16x32_bf16(af[i], bfr[j], acc[i][j], 0, 0, 0);
        }
    }

    float biasv[4];
#pragma unroll
    for (int j = 0; j < 4; ++j)
        biasv[j] = bias[tn * 128 + wn * 64 + j * 16 + lanelo];

#pragma unroll
    for (int i = 0; i < 4; ++i) {
#pragma unroll
        for (int r = 0; r < 4; ++r) {
            int gr = tm * 128 + wm * 64 + i * 16 + quad * 4 + r;   // = b*256 + t
            int bb = gr >> 8, tt = gr & 255;
            size_t orow = (size_t)(tt * 128 + bb) * 512;
#pragma unroll
            for (int j = 0; j < 4; ++j) {
                int col = tn * 128 + wn * 64 + j * 16 + lanelo;
                out[orow + col] = f2b(acc[i][j][r] + biasv[j]);
            }
        }
    }
}

// ---------------------------------------------------------------------------
// Kernel 4: LSTM recurrence, 16 seqs/block, 16 blocks (dir*8 + bgroup).
// Wave w owns gate tiles {w+4k}: per lane i,f,g,o co-located -> register c.
// One barrier per step; h_lds & xbuf double-buffered.
// ---------------------------------------------------------------------------
__global__ __launch_bounds__(256, 1) void lstm_rec(
    const unsigned short* __restrict__ XP,    // [2][256*128][512] bf16, bias folded
    const float* __restrict__ Wfr, const float* __restrict__ Wbr,
    float* __restrict__ Hout)                 // [2][128][128]
{
    __shared__ unsigned short h_lds[2][16 * 136];
    __shared__ unsigned short xbuf[2][16 * 520];

    const int tid  = threadIdx.x;
    const int w    = tid >> 6;
    const int lane = tid & 63;
    const int lanelo = lane & 15;
    const int quad = lane >> 4;
    const int dir  = blockIdx.x >> 3;
    const int b0   = (blockIdx.x & 7) * 16;

    const float* Wr = dir ? Wbr : Wfr;
    const unsigned short* xp = XP + (size_t)dir * 16777216 + (size_t)b0 * 512;

    // Wr -> B-frags. tile tau_k = w + 4k ; gate = k>>1 ; half = k&1
    short8 wrf[8][4];
#pragma unroll
    for (int k = 0; k < 8; ++k) {
        int g = 16 * (w + 4 * k) + lanelo;
#pragma unroll
        for (int ks = 0; ks < 4; ++ks) {
            short8 f;
#pragma unroll
            for (int j = 0; j < 8; ++j)
                f[j] = (short)f2b(Wr[(ks * 32 + quad * 8 + j) * 512 + g]);
            wrf[k][ks] = f;
        }
    }

    for (int i = tid; i < 16 * 136; i += 256) h_lds[0][i] = 0;

    // xp row t (dir-reversed)
    auto rowp = [&](int t) {
        int rt = dir ? (255 - t) : t;
        return xp + (size_t)rt * 65536;
    };

    uint4 r0[4], xA[4], xB[4];
#pragma unroll
    for (int j = 0; j < 4; ++j) r0[j] = *(const uint4*)(rowp(0) + j * 2048 + tid * 8);
#pragma unroll
    for (int j = 0; j < 4; ++j) xA[j] = *(const uint4*)(rowp(1) + j * 2048 + tid * 8);
#pragma unroll
    for (int j = 0; j < 4; ++j) xB[j] = *(const uint4*)(rowp(2) + j * 2048 + tid * 8);

#pragma unroll
    for (int j = 0; j < 4; ++j) {
        int p = j * 256 + tid, seq = p >> 6, col = (p & 63) * 8;
        *(uint4*)(&xbuf[0][seq * 520 + col]) = r0[j];
    }

    float c01[2][4];
#pragma unroll
    for (int h_ = 0; h_ < 2; ++h_)
#pragma unroll
        for (int r = 0; r < 4; ++r) c01[h_][r] = 0.0f;

    __syncthreads();

    for (int t = 0; t < 256; ++t) {
        const int cur = t & 1, nxt = cur ^ 1;

        // A-frags of h (m = seq = lanelo)
        short8 af[4];
#pragma unroll
        for (int ks = 0; ks < 4; ++ks)
            af[ks] = *(const short8*)(&h_lds[cur][lanelo * 136 + ks * 32 + quad * 8]);

        // stage row t+1 into xbuf[nxt]; advance prefetch
        if (t + 1 < 256) {
#pragma unroll
            for (int j = 0; j < 4; ++j) {
                int p = j * 256 + tid, seq = p >> 6, col = (p & 63) * 8;
                *(uint4*)(&xbuf[nxt][seq * 520 + col]) = xA[j];
            }
#pragma unroll
            for (int j = 0; j < 4; ++j) xA[j] = xB[j];
            if (t + 3 < 256) {
#pragma unroll
                for (int j = 0; j < 4; ++j)
                    xB[j] = *(const uint4*)(rowp(t + 3) + j * 2048 + tid * 8);
            }
        }

        // z tiles: init from xp (+bias already folded), then h @ Wr
        f32x4 z[8];
#pragma unroll
        for (int k = 0; k < 8; ++k) {
            int colx = 16 * (w + 4 * k) + lanelo;
            f32x4 a;
#pragma unroll
            for (int r = 0; r < 4; ++r)
                a[r] = b2f(xbuf[cur][(quad * 4 + r) * 520 + colx]);
#pragma unroll
            for (int ks = 0; ks < 4; ++ks)
                a = __builtin_amdgcn_mfma_f32_16x16x32_bf16(af[ks], wrf[k][ks], a, 0, 0, 0);
            z[k] = a;
        }

        // activations + c/h update (all register-local per lane)
#pragma unroll
        for (int h_ = 0; h_ < 2; ++h_) {
#pragma unroll
            for (int r = 0; r < 4; ++r) {
                float iv = sigmoidf_(z[0 + h_][r]);
                float fv = sigmoidf_(z[2 + h_][r]);
                float gv = tanhf_(z[4 + h_][r]);
                float ov = sigmoidf_(z[6 + h_][r]);
                float cc = fv * c01[h_][r] + iv * gv;
                c01[h_][r] = cc;
                float hv = ov * tanhf_(cc);
                int seq = quad * 4 + r;
                int jj = 16 * w + 64 * h_ + lanelo;
                h_lds[nxt][seq * 136 + jj] = f2b(hv);
                if (t == 255)
                    Hout[(size_t)(dir * 128 + b0 + seq) * 128 + jj] = hv;
            }
        }
        __syncthreads();
    }
}

// ---------------------------------------------------------------------------
// Kernel 5: MLP head
// ---------------------------------------------------------------------------
__global__ void mlp_head(const float* __restrict__ Hout,
                         const float* __restrict__ W1, const float* __restrict__ b1,
                         const float* __restrict__ W2, const float* __restrict__ b2,
                         float* __restrict__ out)
{
    __shared__ float y1[32];
    int b = blockIdx.x;
    int j = threadIdx.x;
    const float* hf = Hout + (size_t)b * 128;
    const float* hb = Hout + (size_t)(128 + b) * 128;
    if (j < 32) {
        float acc = b1[j];
        for (int k = 0; k < 128; ++k) acc += hf[k] * W1[k * 32 + j];
        for (int k = 0; k < 128; ++k) acc += hb[k] * W1[(128 + k) * 32 + j];
        y1[j] = fmaxf(acc, 0.0f);
    }
    __syncthreads();
    if (j < 2) {
        float z = b2[j];
        for (int k = 0; k < 32; ++k) z += y1[k] * W2[k * 2 + j];
        out[b * 2 + j] = 1.0f / (1.0f + __expf(-z));
    }
}

// ---------------------------------------------------------------------------
extern "C" void kernel_launch(void* const* d_in, const int* in_sizes, int n_in,
                              void* d_out, int out_size, void* d_ws, size_t ws_size,
                              hipStream_t stream) {
    const float* x    = (const float*)d_in[0];
    const float* Wf_k = (const float*)d_in[1];
    const float* Wf_r = (const float*)d_in[2];
    const float* bf   = (const float*)d_in[3];
    const float* Wb_k = (const float*)d_in[4];
    const float* Wb_r = (const float*)d_in[5];
    const float* bb   = (const float*)d_in[6];
    const float* W1   = (const float*)d_in[7];
    const float* b1   = (const float*)d_in[8];
    const float* W2   = (const float*)d_in[9];
    const float* b2   = (const float*)d_in[10];
    float* out = (float*)d_out;

    char* ws = (char*)d_ws;
    const size_t OFF_XB   = 0;                        // 67,108,864 B
    const size_t OFF_WT   = 67108864;                 //  2,097,152 B
    const size_t OFF_HOUT = OFF_WT + 2097152;         //    131,072 B
    const size_t OFF_XP   = OFF_HOUT + 131072;        // 67,108,864 B (bf16)

    unsigned short* xb = (unsigned short*)(ws + OFF_XB);
    unsigned short* wt = (unsigned short*)(ws + OFF_WT);
    float*          ho = (float*)(ws + OFF_HOUT);
    unsigned short* xp = (unsigned short*)(ws + OFF_XP);

    conv_x<<<dim3(2048), dim3(256), 0, stream>>>(x, xb, 33554432 / 8);
    conv_wk<<<dim3(2048, 2), dim3(256), 0, stream>>>(Wf_k, Wb_k, wt);
    gemm_xp<<<dim3(256, 4, 2), dim3(256), 0, stream>>>(xb, wt, bf, bb, xp);
    lstm_rec<<<dim3(16), dim3(256), 0, stream>>>(xp, Wf_r, Wb_r, ho);
    mlp_head<<<dim3(128), dim3(64), 0, stream>>>(ho, W1, b1, W2, b2, out);
}

// Round 3
// 508.783 us; speedup vs baseline: 2.3150x; 2.3150x over previous
//
#include <hip/hip_runtime.h>
#include <cstdint>
#include <cstddef>

// ---------------------------------------------------------------------------
//   x:    [B=128, T=256, D=1024] fp32
//   Wk:   [1024, 512] per dir    Wr: [128, 512]    bias: [512]
//   xp[dir][t*128+b][512] = x[b,t,:] @ Wk + bias   (bf16, t-major, bias folded)
//   LSTM: 2 seqs/block, 128 blocks (128 CUs). Transposed MFMA (M=gates,
//   N=seqs); z redistributed via LDS so all 256 threads do activations
//   (1 cell value per thread). Lite barriers (lgkmcnt only, no vmcnt drain).
// ---------------------------------------------------------------------------

typedef __attribute__((ext_vector_type(8))) short short8;
typedef __attribute__((ext_vector_type(4))) float f32x4;
typedef __attribute__((address_space(1))) unsigned int gas_uint;
typedef __attribute__((address_space(3))) unsigned int las_uint;

__device__ __forceinline__ unsigned short f2b(float f) {
    unsigned int u = __float_as_uint(f);
    u += 0x7FFFu + ((u >> 16) & 1u);          // RNE
    return (unsigned short)(u >> 16);
}
__device__ __forceinline__ float b2f(unsigned short u) {
    return __uint_as_float(((unsigned int)u) << 16);
}
__device__ __forceinline__ float sigmoidf_(float z) { return 1.0f / (1.0f + __expf(-z)); }
__device__ __forceinline__ float tanhf_(float z) {
    float e = __expf(2.0f * z);
    return 1.0f - 2.0f / (e + 1.0f);
}

// workgroup barrier WITHOUT the vmcnt(0) drain __syncthreads would emit:
// LDS ordering only — outstanding global prefetch loads stay in flight.
#define LITE_BARRIER() asm volatile("s_waitcnt lgkmcnt(0)\n\ts_barrier" ::: "memory")

// async global->LDS 16B
__device__ __forceinline__ void async_ld16(const unsigned short* g, unsigned short* l) {
    __builtin_amdgcn_global_load_lds(
        (gas_uint*)(uintptr_t)g,
        (las_uint*)(uintptr_t)(unsigned int)(uintptr_t)l,
        16, 0, 0);
}

// ---------------------------------------------------------------------------
// Kernel 1: x fp32 -> bf16
// ---------------------------------------------------------------------------
__global__ void conv_x(const float* __restrict__ x, unsigned short* __restrict__ xb, int n8) {
    int idx = blockIdx.x * blockDim.x + threadIdx.x;
    int stride = gridDim.x * blockDim.x;
    for (int i = idx; i < n8; i += stride) {
        const float4* p = ((const float4*)x) + (size_t)i * 2;
        float4 a = p[0], b = p[1];
        short8 r;
        r[0] = (short)f2b(a.x); r[1] = (short)f2b(a.y);
        r[2] = (short)f2b(a.z); r[3] = (short)f2b(a.w);
        r[4] = (short)f2b(b.x); r[5] = (short)f2b(b.y);
        r[6] = (short)f2b(b.z); r[7] = (short)f2b(b.w);
        *(((short8*)xb) + i) = r;
    }
}

// ---------------------------------------------------------------------------
// Kernel 2: transpose + convert Wk [1024][512] -> Wk_t [512][1024] bf16
// ---------------------------------------------------------------------------
__global__ void conv_wk(const float* __restrict__ wf, const float* __restrict__ wb,
                        unsigned short* __restrict__ wt) {
    int dir = blockIdx.y;
    const float* w = dir ? wb : wf;
    int id = blockIdx.x * blockDim.x + threadIdx.x;
    int g = id >> 10, d = id & 1023;
    wt[(size_t)dir * 524288 + id] = f2b(w[d * 512 + g]);
}

// ---------------------------------------------------------------------------
// Kernel 3: GEMM xp = A[32768,1024] @ Wk_t^T + bias -> bf16 t-major [t*128+b][512]
// (unchanged from R2: 128x128 tile, BK=64, global_load_lds w=16, XOR swizzle)
// ---------------------------------------------------------------------------
__global__ __launch_bounds__(256, 2) void gemm_xp(
    const unsigned short* __restrict__ A,
    const unsigned short* __restrict__ Wt,
    const float* __restrict__ bf_, const float* __restrict__ bb_,
    unsigned short* __restrict__ XP)
{
    __shared__ unsigned short As[128 * 64];
    __shared__ unsigned short Bs[128 * 64];

    const int tid  = threadIdx.x;
    const int dir  = blockIdx.z;
    const int tm   = blockIdx.x;             // 0..255
    const int tn   = blockIdx.y;             // 0..3
    const int w    = tid >> 6;
    const int lane = tid & 63;
    const int lanelo = lane & 15;
    const int quad = lane >> 4;
    const int wm = w & 1, wn = w >> 1;

    const unsigned short* Bmat = Wt + (size_t)dir * 524288;
    const float* bias = dir ? bb_ : bf_;
    unsigned short* out = XP + (size_t)dir * 16777216;

    const unsigned short* ga[4];
    const unsigned short* gb[4];
    unsigned short* la[4];
    unsigned short* lb[4];
#pragma unroll
    for (int c = 0; c < 4; ++c) {
        int p = c * 256 + tid;
        int row = p >> 3;
        int lc = (p & 7) ^ (row & 7);
        ga[c] = A    + (size_t)(tm * 128 + row) * 1024 + lc * 8;
        gb[c] = Bmat + (size_t)(tn * 128 + row) * 1024 + lc * 8;
        int ub = (c * 256 + (tid & ~63)) * 8;
        la[c] = As + ub;
        lb[c] = Bs + ub;
    }

    f32x4 acc[4][4];
#pragma unroll
    for (int i = 0; i < 4; i++)
#pragma unroll
        for (int j = 0; j < 4; j++) acc[i][j] = (f32x4){0.f, 0.f, 0.f, 0.f};

    for (int kt = 0; kt < 16; ++kt) {
        __syncthreads();
#pragma unroll
        for (int c = 0; c < 4; ++c) {
            async_ld16(ga[c] + kt * 64, la[c]);
            async_ld16(gb[c] + kt * 64, lb[c]);
        }
        __syncthreads();
#pragma unroll
        for (int ks = 0; ks < 2; ++ks) {
            short8 af[4], bfr[4];
#pragma unroll
            for (int i = 0; i < 4; ++i) {
                int row = wm * 64 + i * 16 + lanelo;
                af[i] = *(const short8*)(As + row * 64 + (((ks * 4 + quad) ^ (row & 7)) * 8));
            }
#pragma unroll
            for (int j = 0; j < 4; ++j) {
                int row = wn * 64 + j * 16 + lanelo;
                bfr[j] = *(const short8*)(Bs + row * 64 + (((ks * 4 + quad) ^ (row & 7)) * 8));
            }
#pragma unroll
            for (int i = 0; i < 4; ++i)
#pragma unroll
                for (int j = 0; j < 4; ++j)
                    acc[i][j] = __builtin_amdgcn_mfma_f32_16x16x32_bf16(af[i], bfr[j], acc[i][j], 0, 0, 0);
        }
    }

    float biasv[4];
#pragma unroll
    for (int j = 0; j < 4; ++j)
        biasv[j] = bias[tn * 128 + wn * 64 + j * 16 + lanelo];

#pragma unroll
    for (int i = 0; i < 4; ++i) {
#pragma unroll
        for (int r = 0; r < 4; ++r) {
            int gr = tm * 128 + wm * 64 + i * 16 + quad * 4 + r;   // = b*256 + t
            int bb = gr >> 8, tt = gr & 255;
            size_t orow = (size_t)(tt * 128 + bb) * 512;
#pragma unroll
            for (int j = 0; j < 4; ++j) {
                int col = tn * 128 + wn * 64 + j * 16 + lanelo;
                out[orow + col] = f2b(acc[i][j][r] + biasv[j]);
            }
        }
    }
}

// ---------------------------------------------------------------------------
// Kernel 4: LSTM recurrence. 128 blocks x 256 thr; block = (dir, seq-pair).
// Transposed MFMA: A = Wr^T tiles (M=gate rows, wave w owns [128w,128w+128)),
// B = h (N=seq, cols 0..1 valid). z -> LDS -> flat activation (thread owns
// one (seq,dim) cell: all 4 gates + c). xp read as 4 coalesced ushort/step.
// ---------------------------------------------------------------------------
__global__ __launch_bounds__(256, 1) void lstm_rec(
    const unsigned short* __restrict__ XP,    // [2][256*128][512] bf16, bias folded
    const float* __restrict__ Wfr, const float* __restrict__ Wbr,
    float* __restrict__ Hout)                 // [2][128][128]
{
    __shared__ float zbuf[2][512];            // [seq][gate]
    __shared__ unsigned short h_lds[2][2][128]; // [buf][seq][dim]

    const int tid    = threadIdx.x;
    const int w      = tid >> 6;
    const int lane   = tid & 63;
    const int lanelo = lane & 15;
    const int quad   = lane >> 4;
    const int dir    = blockIdx.x >> 6;
    const int b0     = (blockIdx.x & 63) * 2;

    const float* Wr = dir ? Wbr : Wfr;
    const unsigned short* xp = XP + (size_t)dir * 16777216;

    // --- one-time: Wr^T A-fragments. wave w owns gate rows [128w, 128w+128) ---
    short8 wrf[8][4];
#pragma unroll
    for (int kt = 0; kt < 8; ++kt) {
        int g = 128 * w + 16 * kt + lanelo;
#pragma unroll
        for (int ks = 0; ks < 4; ++ks) {
            short8 f;
#pragma unroll
            for (int j = 0; j < 8; ++j)
                f[j] = (short)f2b(Wr[(ks * 32 + quad * 8 + j) * 512 + g]);
            wrf[kt][ks] = f;
        }
    }

    // activation cell owned by this thread
    const int aseq = tid >> 7;               // 0..1
    const int adim = tid & 127;              // 0..127
    const int arow = b0 + aseq;              // batch index

    h_lds[0][aseq][adim] = 0;

    float c_val = 0.0f;
    float h_val = 0.0f;

    // xp address for step t, gate g
    auto xaddr = [&](int t, int g) {
        int rt = dir ? (255 - t) : t;
        return xp + (size_t)rt * 65536 + (size_t)arow * 512 + g * 128 + adim;
    };

    unsigned int xA[4], xB[4];
#pragma unroll
    for (int g = 0; g < 4; ++g) xA[g] = *xaddr(0, g);
#pragma unroll
    for (int g = 0; g < 4; ++g) xB[g] = *xaddr(1, g);

    LITE_BARRIER();                           // h_lds[0] zeros visible

    for (int t = 0; t < 256; ++t) {
        const int cur = t & 1, nxt = cur ^ 1;

        // prefetch xp for t+2 (stays in flight across lite barriers)
        unsigned int xN[4];
        if (t + 2 < 256) {
#pragma unroll
            for (int g = 0; g < 4; ++g) xN[g] = *xaddr(t + 2, g);
        }

        // B-fragments of h (n = seq; lanes >=2 alias seq lanelo&1, ignored)
        short8 hb[4];
#pragma unroll
        for (int ks = 0; ks < 4; ++ks)
            hb[ks] = *(const short8*)(&h_lds[cur][lanelo & 1][ks * 32 + quad * 8]);

        // z = Wr^T tiles @ h : D[m=gate][n=seq]
        f32x4 z[8];
#pragma unroll
        for (int kt = 0; kt < 8; ++kt) {
            f32x4 a = (f32x4){0.f, 0.f, 0.f, 0.f};
#pragma unroll
            for (int ks = 0; ks < 4; ++ks)
                a = __builtin_amdgcn_mfma_f32_16x16x32_bf16(wrf[kt][ks], hb[ks], a, 0, 0, 0);
            z[kt] = a;
        }

        // scatter z to LDS: C/D row = quad*4+r (gate sub-row), col = lanelo (seq)
        if (lanelo < 2) {
#pragma unroll
            for (int kt = 0; kt < 8; ++kt)
                *(f32x4*)(&zbuf[lanelo][128 * w + 16 * kt + quad * 4]) = z[kt];
        }

        LITE_BARRIER();                       // z visible

        float zi = zbuf[aseq][adim]       + b2f((unsigned short)xA[0]);
        float zf = zbuf[aseq][128 + adim] + b2f((unsigned short)xA[1]);
        float zg = zbuf[aseq][256 + adim] + b2f((unsigned short)xA[2]);
        float zo = zbuf[aseq][384 + adim] + b2f((unsigned short)xA[3]);

        float iv = sigmoidf_(zi);
        float fv = sigmoidf_(zf);
        float gv = tanhf_(zg);
        float ov = sigmoidf_(zo);
        c_val = fv * c_val + iv * gv;
        h_val = ov * tanhf_(c_val);

        h_lds[nxt][aseq][adim] = f2b(h_val);

#pragma unroll
        for (int g = 0; g < 4; ++g) { xA[g] = xB[g]; xB[g] = xN[g]; }

        LITE_BARRIER();                       // h(t) visible, zbuf reads done
    }

    Hout[(size_t)(dir * 128 + arow) * 128 + adim] = h_val;
}

// ---------------------------------------------------------------------------
// Kernel 5: MLP head
// ---------------------------------------------------------------------------
__global__ void mlp_head(const float* __restrict__ Hout,
                         const float* __restrict__ W1, const float* __restrict__ b1,
                         const float* __restrict__ W2, const float* __restrict__ b2,
                         float* __restrict__ out)
{
    __shared__ float y1[32];
    int b = blockIdx.x;
    int j = threadIdx.x;
    const float* hf = Hout + (size_t)b * 128;
    const float* hb = Hout + (size_t)(128 + b) * 128;
    if (j < 32) {
        float acc = b1[j];
        for (int k = 0; k < 128; ++k) acc += hf[k] * W1[k * 32 + j];
        for (int k = 0; k < 128; ++k) acc += hb[k] * W1[(128 + k) * 32 + j];
        y1[j] = fmaxf(acc, 0.0f);
    }
    __syncthreads();
    if (j < 2) {
        float z = b2[j];
        for (int k = 0; k < 32; ++k) z += y1[k] * W2[k * 2 + j];
        out[b * 2 + j] = 1.0f / (1.0f + __expf(-z));
    }
}

// ---------------------------------------------------------------------------
extern "C" void kernel_launch(void* const* d_in, const int* in_sizes, int n_in,
                              void* d_out, int out_size, void* d_ws, size_t ws_size,
                              hipStream_t stream) {
    const float* x    = (const float*)d_in[0];
    const float* Wf_k = (const float*)d_in[1];
    const float* Wf_r = (const float*)d_in[2];
    const float* bf   = (const float*)d_in[3];
    const float* Wb_k = (const float*)d_in[4];
    const float* Wb_r = (const float*)d_in[5];
    const float* bb   = (const float*)d_in[6];
    const float* W1   = (const float*)d_in[7];
    const float* b1   = (const float*)d_in[8];
    const float* W2   = (const float*)d_in[9];
    const float* b2   = (const float*)d_in[10];
    float* out = (float*)d_out;

    char* ws = (char*)d_ws;
    const size_t OFF_XB   = 0;                        // 67,108,864 B
    const size_t OFF_WT   = 67108864;                 //  2,097,152 B
    const size_t OFF_HOUT = OFF_WT + 2097152;         //    131,072 B
    const size_t OFF_XP   = OFF_HOUT + 131072;        // 67,108,864 B (bf16)

    unsigned short* xb = (unsigned short*)(ws + OFF_XB);
    unsigned short* wt = (unsigned short*)(ws + OFF_WT);
    float*          ho = (float*)(ws + OFF_HOUT);
    unsigned short* xp = (unsigned short*)(ws + OFF_XP);

    conv_x<<<dim3(2048), dim3(256), 0, stream>>>(x, xb, 33554432 / 8);
    conv_wk<<<dim3(2048, 2), dim3(256), 0, stream>>>(Wf_k, Wb_k, wt);
    gemm_xp<<<dim3(256, 4, 2), dim3(256), 0, stream>>>(xb, wt, bf, bb, xp);
    lstm_rec<<<dim3(128), dim3(256), 0, stream>>>(xp, Wf_r, Wb_r, ho);
    mlp_head<<<dim3(128), dim3(64), 0, stream>>>(ho, W1, b1, W2, b2, out);
}